// Round 14
// baseline (88.222 us; speedup 1.0000x reference)
//
#include <hip/hip_runtime.h>
#include <hip/hip_bf16.h>
#include <stdint.h>

#define NNODES 10000
#define NEDGES 320000
#define DIM    256
#define KTOT   512
#define LN_EPS 1e-5f
#define BCAP   96     // per-node bucket capacity (max degree; P(exceed) ~ 1e-20)

typedef __attribute__((ext_vector_type(4))) float f32x4;
typedef __attribute__((ext_vector_type(8))) short bf16x8;

__device__ __forceinline__ ushort f2bf(float f) {
    union { float f; uint32_t u; } v; v.f = f;
    uint32_t r = v.u + 0x7fffu + ((v.u >> 16) & 1u);   // RNE
    return (ushort)(r >> 16);
}
__device__ __forceinline__ float bf2f(ushort u) {
    union { float f; uint32_t u; } v; v.u = ((uint32_t)u) << 16;
    return v.f;
}

// ---- K1: prep — cast x->bf16, zero cnt, fragment-arrange both W matrices ----
__global__ __launch_bounds__(256)
void prep_all(const float* __restrict__ x, const float* __restrict__ Wm,
              const float* __restrict__ Wu, ushort* __restrict__ xb,
              ushort* __restrict__ Wcat, ushort* __restrict__ Wua,
              int4* __restrict__ cntz) {
    int tid = blockIdx.x * 256 + threadIdx.x;          // 3524*256 = 902144
    if (tid < 2560) cntz[tid] = (int4){0, 0, 0, 0};    // 10240 ints >= NNODES
    if (tid < 640000) {                                // x cast, one float4 each
        float4 v = reinterpret_cast<const float4*>(x)[tid];
        ushort4 o;
        o.x = f2bf(v.x); o.y = f2bf(v.y); o.z = f2bf(v.z); o.w = f2bf(v.w);
        reinterpret_cast<ushort4*>(xb)[tid] = o;
    } else {
        int t = tid - 640000;                          // < 262144
        if (t < 131072) {
            int kk  = t >> 14;
            int rem = t & 16383;
            int g   = rem >> 9;
            int kg  = (rem >> 7) & 3;
            int ml  = (rem >> 3) & 15;
            int j   = rem & 7;
            int k = kk * 32 + kg * 8 + j;
            int n = g * 16 + ml;
            float v = (n < 256) ? Wm[k * DIM + n] : Wm[(k + 256) * DIM + (n - 256)];
            Wcat[t] = f2bf(v);
        } else {
            int rem = t - 131072;
            int kk  = rem >> 13;
            int nt  = (rem >> 9) & 15;
            int kg  = (rem >> 7) & 3;
            int ml  = (rem >> 3) & 15;
            int j   = rem & 7;
            int k = kk * 32 + kg * 8 + j;
            int n = nt * 16 + ml;
            Wua[rem] = f2bf(Wu[k * DIM + n]);
        }
    }
}

// ---- K2: bucket scatter (blocks [0,1250)) ∥ U|V GEMM (blocks [1250,1875)) ----
__global__ __launch_bounds__(256)
void scatter_uv(const int* __restrict__ eidx, int* __restrict__ cnt,
                int* __restrict__ srow, const ushort* __restrict__ xb,
                const ushort* __restrict__ Wcat, const float* __restrict__ bmsg,
                ushort* __restrict__ Ub, float* __restrict__ Vf) {
    if (blockIdx.x < 1250) {
        int e = blockIdx.x * 256 + threadIdx.x;        // 1250*256 = 320000 exact
        int d = eidx[NEDGES + e];
        int p = atomicAdd(&cnt[d], 1);
        if (p < BCAP) srow[d * BCAP + p] = eidx[e];
        return;
    }
    // U = x @ W_msg[:256] (bf16), V = x @ W_msg[256:] + b (fp32)
    const int wq   = threadIdx.x >> 6;
    const int lane = threadIdx.x & 63;
    const int ml = lane & 15, kg = lane >> 4;
    const int nb = (blockIdx.x - 1250) * 16;
    const uint arow = (uint)(nb + ml) * DIM;

    f32x4 acc[8];
#pragma unroll
    for (int nt = 0; nt < 8; ++nt) acc[nt] = (f32x4){0.f, 0.f, 0.f, 0.f};

#pragma unroll
    for (int kk = 0; kk < 8; ++kk) {
        bf16x8 a = *reinterpret_cast<const bf16x8*>(xb + arow + kk * 32 + kg * 8);
#pragma unroll
        for (int nt = 0; nt < 8; ++nt) {
            bf16x8 b = *reinterpret_cast<const bf16x8*>(Wcat + kk * 16384 + (wq * 8 + nt) * 512 + lane * 8);
            acc[nt] = __builtin_amdgcn_mfma_f32_16x16x32_bf16(a, b, acc[nt], 0, 0, 0);
        }
    }

    if (wq < 2) {                                   // U half: bf16
#pragma unroll
        for (int nt = 0; nt < 8; ++nt) {
            const int col = wq * 128 + nt * 16 + ml;
#pragma unroll
            for (int i = 0; i < 4; ++i)
                Ub[(size_t)(nb + kg * 4 + i) * 256 + col] = f2bf(acc[nt][i]);
        }
    } else {                                        // V half: fp32, bias folded
#pragma unroll
        for (int nt = 0; nt < 8; ++nt) {
            const int col = (wq - 2) * 128 + nt * 16 + ml;
            const float bb = bmsg[col];
#pragma unroll
            for (int i = 0; i < 4; ++i)
                Vf[(size_t)(nb + kg * 4 + i) * 256 + col] = acc[nt][i] + bb;
        }
    }
}

// ---- K3: fused edge-combine + node GEMM + LayerNorm ----
// 1250 blocks x 512 thr (8 waves) = 8 nodes/block; 10000 waves total (39/CU,
// oversubscribed -> queued waves backfill the degree-straggler tail).
// Phase A: wave w reduces node nb+w ALONE. Lane owns 8 cols (16B U loads);
//   32-lane halves split edges by parity with 8-DEEP load ILP (one iteration
//   covers a typical node's entire half-list); one shfl_xor(32) combine.
// Phase B: k<256 MFMA half hoisted before the barrier; k>=256 from aggS;
//   8 waves x 32 cols, A-rows 8..15 duplicate 0..7, writes guarded kg<2.
__global__ __launch_bounds__(512)
void edge_node(const ushort* __restrict__ Ub, const float* __restrict__ Vf,
               const int* __restrict__ srow, const int* __restrict__ cnt,
               const ushort* __restrict__ xb, const ushort* __restrict__ Wua,
               const float* __restrict__ bupd, const float* __restrict__ gamma,
               const float* __restrict__ beta, float* __restrict__ out) {
    __shared__ float aggS[8][260];      // +4 pad
    __shared__ float pS[16][8][2];      // LN partials [row][wave][sum,ssq]

    const int tid  = threadIdx.x;
    const int wave = tid >> 6, lane = tid & 63;
    const int nb = blockIdx.x * 8;
    const int el = lane >> 5;           // half id (edge-parity)
    const int cl = lane & 31;
    const int c0 = cl * 8;              // 8 cols owned

    // ---- Phase A: one node per wave, 8-deep gather ----
    {
        const int d = nb + wave;
        int deg = cnt[d]; deg = deg < BCAP ? deg : BCAP;
        const int beg = d * BCAP;
        const float4 va = *reinterpret_cast<const float4*>(&Vf[(size_t)d * 256 + c0]);
        const float4 vb = *reinterpret_cast<const float4*>(&Vf[(size_t)d * 256 + c0 + 4]);
        float s[8];
#pragma unroll
        for (int j = 0; j < 8; ++j) s[j] = 0.f;

#define ACC8(U) do { \
        s[0] += fmaxf(bf2f((ushort)(U)[0]) + va.x, 0.f); \
        s[1] += fmaxf(bf2f((ushort)(U)[1]) + va.y, 0.f); \
        s[2] += fmaxf(bf2f((ushort)(U)[2]) + va.z, 0.f); \
        s[3] += fmaxf(bf2f((ushort)(U)[3]) + va.w, 0.f); \
        s[4] += fmaxf(bf2f((ushort)(U)[4]) + vb.x, 0.f); \
        s[5] += fmaxf(bf2f((ushort)(U)[5]) + vb.y, 0.f); \
        s[6] += fmaxf(bf2f((ushort)(U)[6]) + vb.z, 0.f); \
        s[7] += fmaxf(bf2f((ushort)(U)[7]) + vb.w, 0.f); } while (0)

        int i = el;                      // this half: indices el, el+2, el+4, ...
        for (; i + 14 < deg; i += 16) {  // 8 rows in flight per half
            int r[8];
#pragma unroll
            for (int j = 0; j < 8; ++j) r[j] = srow[beg + i + 2 * j];
            bf16x8 u[8];
#pragma unroll
            for (int j = 0; j < 8; ++j)
                u[j] = *reinterpret_cast<const bf16x8*>(&Ub[(size_t)r[j] * 256 + c0]);
#pragma unroll
            for (int j = 0; j < 8; ++j) ACC8(u[j]);
        }
        for (; i < deg; i += 2) {
            int r = srow[beg + i];
            bf16x8 u = *reinterpret_cast<const bf16x8*>(&Ub[(size_t)r * 256 + c0]);
            ACC8(u);
        }
#undef ACC8
#pragma unroll
        for (int j = 0; j < 8; ++j) s[j] += __shfl_xor(s[j], 32);
        if (el == 0) {
            *reinterpret_cast<float4*>(&aggS[wave][c0])     = (float4){s[0], s[1], s[2], s[3]};
            *reinterpret_cast<float4*>(&aggS[wave][c0 + 4]) = (float4){s[4], s[5], s[6], s[7]};
        }
    }

    // ---- Phase B, k<256 half (independent of aggS -> before barrier) ----
    const int ml = lane & 15, kg = lane >> 4, wq = wave;
    const uint arow = (uint)(nb + (ml & 7)) * DIM;    // rows 8..15 duplicate 0..7

    f32x4 acc[2];
    acc[0] = (f32x4){0.f, 0.f, 0.f, 0.f};
    acc[1] = (f32x4){0.f, 0.f, 0.f, 0.f};

#pragma unroll
    for (int kk = 0; kk < 8; ++kk) {
        bf16x8 a = *reinterpret_cast<const bf16x8*>(xb + arow + kk * 32 + kg * 8);
#pragma unroll
        for (int nt = 0; nt < 2; ++nt) {
            bf16x8 b = *reinterpret_cast<const bf16x8*>(Wua + kk * 8192 + (wq * 2 + nt) * 512 + lane * 8);
            acc[nt] = __builtin_amdgcn_mfma_f32_16x16x32_bf16(a, b, acc[nt], 0, 0, 0);
        }
    }
    __syncthreads();

    // ---- Phase B, k>=256 half: A from aggS ----
#pragma unroll
    for (int kk = 0; kk < 8; ++kk) {
        float4 f0 = *reinterpret_cast<const float4*>(&aggS[ml & 7][kk * 32 + kg * 8]);
        float4 f1 = *reinterpret_cast<const float4*>(&aggS[ml & 7][kk * 32 + kg * 8 + 4]);
        union { bf16x8 v; __hip_bfloat162 h2[4]; } u;
        u.h2[0] = __float22bfloat162_rn(make_float2(f0.x, f0.y));
        u.h2[1] = __float22bfloat162_rn(make_float2(f0.z, f0.w));
        u.h2[2] = __float22bfloat162_rn(make_float2(f1.x, f1.y));
        u.h2[3] = __float22bfloat162_rn(make_float2(f1.z, f1.w));
#pragma unroll
        for (int nt = 0; nt < 2; ++nt) {
            bf16x8 b = *reinterpret_cast<const bf16x8*>(Wua + 65536 + kk * 8192 + (wq * 2 + nt) * 512 + lane * 8);
            acc[nt] = __builtin_amdgcn_mfma_f32_16x16x32_bf16(u.v, b, acc[nt], 0, 0, 0);
        }
    }

    // bias + relu + per-wave LN partials (32 cols per wave)
    float sum[4] = {0.f, 0.f, 0.f, 0.f}, ssq[4] = {0.f, 0.f, 0.f, 0.f};
#pragma unroll
    for (int nt = 0; nt < 2; ++nt) {
        const float bb = bupd[(wq * 2 + nt) * 16 + ml];
#pragma unroll
        for (int i = 0; i < 4; ++i) {
            float v = acc[nt][i] + bb;
            v = v > 0.f ? v : 0.f;
            acc[nt][i] = v;
            sum[i] += v;
            ssq[i] += v * v;
        }
    }
#pragma unroll
    for (int m = 1; m < 16; m <<= 1) {
#pragma unroll
        for (int i = 0; i < 4; ++i) {
            sum[i] += __shfl_xor(sum[i], m);
            ssq[i] += __shfl_xor(ssq[i], m);
        }
    }
    if (ml == 0) {
#pragma unroll
        for (int i = 0; i < 4; ++i) {
            pS[kg * 4 + i][wq][0] = sum[i];
            pS[kg * 4 + i][wq][1] = ssq[i];
        }
    }
    __syncthreads();

    float mu[4], rs[4];
#pragma unroll
    for (int i = 0; i < 4; ++i) {
        int r = kg * 4 + i;
        float S = 0.f, Q = 0.f;
#pragma unroll
        for (int w = 0; w < 8; ++w) { S += pS[r][w][0]; Q += pS[r][w][1]; }
        float m = S * (1.f / 256.f);
        float var = Q * (1.f / 256.f) - m * m;
        mu[i] = m;
        rs[i] = rsqrtf(var + LN_EPS);
    }
    if (kg < 2) {                                     // rows 0..7 = real nodes
#pragma unroll
        for (int nt = 0; nt < 2; ++nt) {
            const int cc = (wq * 2 + nt) * 16 + ml;
            const float g = gamma[cc], be = beta[cc];
#pragma unroll
            for (int i = 0; i < 4; ++i) {
                const int node = nb + kg * 4 + i;
                out[(size_t)node * DIM + cc] = (acc[nt][i] - mu[i]) * rs[i] * g + be;
            }
        }
    }
}

extern "C" void kernel_launch(void* const* d_in, const int* in_sizes, int n_in,
                              void* d_out, int out_size, void* d_ws, size_t ws_size,
                              hipStream_t stream) {
    const float* x    = (const float*)d_in[0];
    const int*   eidx = (const int*)  d_in[1];
    const float* Wm   = (const float*)d_in[2];
    const float* bm   = (const float*)d_in[3];
    const float* Wu   = (const float*)d_in[4];
    const float* bu   = (const float*)d_in[5];
    const float* gam  = (const float*)d_in[6];
    const float* bet  = (const float*)d_in[7];
    float* out = (float*)d_out;

    char* ws = (char*)d_ws;
    ushort* xb     = (ushort*)(ws);                    //  5,120,000 B
    ushort* Ub     = (ushort*)(ws +  5120000);         //  5,120,000 B
    float*  Vf     = (float*) (ws + 10240000);         // 10,240,000 B
    ushort* Wcat   = (ushort*)(ws + 20480000);         //    262,144 B
    ushort* Wua    = (ushort*)(ws + 20742144);         //    262,144 B
    int*    cnt    = (int*)   (ws + 21004288);         //     40,960 B
    int*    srow   = (int*)   (ws + 21045248);         //  3,840,000 B (end ~24.9 MB)

    prep_all<<<3524, 256, 0, stream>>>(x, Wm, Wu, xb, Wcat, Wua, (int4*)cnt);
    scatter_uv<<<1875, 256, 0, stream>>>(eidx, cnt, srow, xb, Wcat, bm, Ub, Vf);
    edge_node<<<NNODES / 8, 512, 0, stream>>>(Ub, Vf, srow, cnt, xb, Wua, bu, gam, bet, out);
}

// Round 15
// 87.408 us; speedup vs baseline: 1.0093x; 1.0093x over previous
//
#include <hip/hip_runtime.h>
#include <hip/hip_bf16.h>
#include <stdint.h>

#define NNODES 10000
#define NEDGES 320000
#define DIM    256
#define KTOT   512
#define LN_EPS 1e-5f
#define BCAP   96     // per-node bucket capacity (max degree; P(exceed) ~ 1e-20)

typedef __attribute__((ext_vector_type(4))) float f32x4;
typedef __attribute__((ext_vector_type(8))) short bf16x8;

__device__ __forceinline__ ushort f2bf(float f) {
    union { float f; uint32_t u; } v; v.f = f;
    uint32_t r = v.u + 0x7fffu + ((v.u >> 16) & 1u);   // RNE
    return (ushort)(r >> 16);
}
__device__ __forceinline__ float bf2f(ushort u) {
    union { float f; uint32_t u; } v; v.u = ((uint32_t)u) << 16;
    return v.f;
}

// ---- K1: prep — cast x->bf16, zero cnt, fragment-arrange both W matrices ----
__global__ __launch_bounds__(256)
void prep_all(const float* __restrict__ x, const float* __restrict__ Wm,
              const float* __restrict__ Wu, ushort* __restrict__ xb,
              ushort* __restrict__ Wcat, ushort* __restrict__ Wua,
              int4* __restrict__ cntz) {
    int tid = blockIdx.x * 256 + threadIdx.x;          // 3524*256 = 902144
    if (tid < 2560) cntz[tid] = (int4){0, 0, 0, 0};    // 10240 ints >= NNODES
    if (tid < 640000) {                                // x cast, one float4 each
        float4 v = reinterpret_cast<const float4*>(x)[tid];
        ushort4 o;
        o.x = f2bf(v.x); o.y = f2bf(v.y); o.z = f2bf(v.z); o.w = f2bf(v.w);
        reinterpret_cast<ushort4*>(xb)[tid] = o;
    } else {
        int t = tid - 640000;                          // < 262144
        if (t < 131072) {
            int kk  = t >> 14;
            int rem = t & 16383;
            int g   = rem >> 9;
            int kg  = (rem >> 7) & 3;
            int ml  = (rem >> 3) & 15;
            int j   = rem & 7;
            int k = kk * 32 + kg * 8 + j;
            int n = g * 16 + ml;
            float v = (n < 256) ? Wm[k * DIM + n] : Wm[(k + 256) * DIM + (n - 256)];
            Wcat[t] = f2bf(v);
        } else {
            int rem = t - 131072;
            int kk  = rem >> 13;
            int nt  = (rem >> 9) & 15;
            int kg  = (rem >> 7) & 3;
            int ml  = (rem >> 3) & 15;
            int j   = rem & 7;
            int k = kk * 32 + kg * 8 + j;
            int n = nt * 16 + ml;
            Wua[rem] = f2bf(Wu[k * DIM + n]);
        }
    }
}

// ---- K2: bucket scatter (blocks [0,1250)) ∥ U|V GEMM 64-node tiles ([1250,1407)) ----
__global__ __launch_bounds__(512)
void scatter_uv(const int* __restrict__ eidx, int* __restrict__ cnt,
                int* __restrict__ srow, const ushort* __restrict__ xb,
                const ushort* __restrict__ Wcat, const float* __restrict__ bmsg,
                ushort* __restrict__ Ub, float* __restrict__ Vf) {
    if (blockIdx.x < 1250) {
        int e = blockIdx.x * 256 + (threadIdx.x & 255);    // use half the block
        if (threadIdx.x < 256) {
            int d = eidx[NEDGES + e];
            int p = atomicAdd(&cnt[d], 1);
            if (p < BCAP) srow[d * BCAP + p] = eidx[e];
        }
        return;
    }
    // U|V GEMM: 64 nodes x 512 cols per block; wave (wr=wave>>2, wc=wave&3):
    // 32 nodes (t=0,1) x 128 cols (nt=0..7). K = 256.
    const int wave = threadIdx.x >> 6;
    const int lane = threadIdx.x & 63;
    const int ml = lane & 15, kg = lane >> 4;
    const int wr = wave >> 2, wc = wave & 3;
    const int nb = (blockIdx.x - 1250) * 64;

    uint arow[2];
#pragma unroll
    for (int t = 0; t < 2; ++t) {
        int n = nb + wr * 32 + t * 16 + ml;
        arow[t] = (uint)(n < NNODES ? n : NNODES - 1) * DIM;
    }

    f32x4 acc[2][8];
#pragma unroll
    for (int t = 0; t < 2; ++t)
#pragma unroll
        for (int nt = 0; nt < 8; ++nt) acc[t][nt] = (f32x4){0.f, 0.f, 0.f, 0.f};

#pragma unroll
    for (int kk = 0; kk < 8; ++kk) {
        bf16x8 a0 = *reinterpret_cast<const bf16x8*>(xb + arow[0] + kk * 32 + kg * 8);
        bf16x8 a1 = *reinterpret_cast<const bf16x8*>(xb + arow[1] + kk * 32 + kg * 8);
#pragma unroll
        for (int nt = 0; nt < 8; ++nt) {
            bf16x8 b = *reinterpret_cast<const bf16x8*>(Wcat + kk * 16384 + (wc * 8 + nt) * 512 + lane * 8);
            acc[0][nt] = __builtin_amdgcn_mfma_f32_16x16x32_bf16(a0, b, acc[0][nt], 0, 0, 0);
            acc[1][nt] = __builtin_amdgcn_mfma_f32_16x16x32_bf16(a1, b, acc[1][nt], 0, 0, 0);
        }
    }

    if (wc < 2) {                                   // U half: bf16
#pragma unroll
        for (int t = 0; t < 2; ++t)
#pragma unroll
            for (int nt = 0; nt < 8; ++nt) {
                const int col = wc * 128 + nt * 16 + ml;
#pragma unroll
                for (int i = 0; i < 4; ++i) {
                    int node = nb + wr * 32 + t * 16 + kg * 4 + i;
                    if (node < NNODES) Ub[(size_t)node * 256 + col] = f2bf(acc[t][nt][i]);
                }
            }
    } else {                                        // V half: fp32, bias folded
#pragma unroll
        for (int t = 0; t < 2; ++t)
#pragma unroll
            for (int nt = 0; nt < 8; ++nt) {
                const int col = (wc - 2) * 128 + nt * 16 + ml;
                const float bb = bmsg[col];
#pragma unroll
                for (int i = 0; i < 4; ++i) {
                    int node = nb + wr * 32 + t * 16 + kg * 4 + i;
                    if (node < NNODES) Vf[(size_t)node * 256 + col] = acc[t][nt][i] + bb;
                }
            }
    }
}

// ---- K3: edge combine (standalone, no barrier): aggb[d] = bf16 of
//          sum over bucket(d) of relu(U[src] + V[d]).
// 1250 blocks x 256 thr (4 waves); wave reduces 2 nodes (R13-proven shape):
// lane owns 8 cols (16B loads), 32-lane halves split edges by parity with
// 4-deep ILP, one shfl_xor(32) combine, bf16x8 store.
__global__ __launch_bounds__(256)
void edge_combine(const ushort* __restrict__ Ub, const float* __restrict__ Vf,
                  const int* __restrict__ srow, const int* __restrict__ cnt,
                  ushort* __restrict__ aggb) {
    const int wave = threadIdx.x >> 6, lane = threadIdx.x & 63;
    const int nb = blockIdx.x * 8;
    const int el = lane >> 5;           // half id (edge-parity)
    const int cl = lane & 31;
    const int c0 = cl * 8;              // 8 cols owned

#pragma unroll
    for (int nn = 0; nn < 2; ++nn) {
        const int d = nb + wave * 2 + nn;
        int deg = cnt[d]; deg = deg < BCAP ? deg : BCAP;
        const int beg = d * BCAP;
        const float4 va = *reinterpret_cast<const float4*>(&Vf[(size_t)d * 256 + c0]);
        const float4 vb = *reinterpret_cast<const float4*>(&Vf[(size_t)d * 256 + c0 + 4]);
        float s[8];
#pragma unroll
        for (int j = 0; j < 8; ++j) s[j] = 0.f;

#define ACC8(U) do { \
        s[0] += fmaxf(bf2f((ushort)(U)[0]) + va.x, 0.f); \
        s[1] += fmaxf(bf2f((ushort)(U)[1]) + va.y, 0.f); \
        s[2] += fmaxf(bf2f((ushort)(U)[2]) + va.z, 0.f); \
        s[3] += fmaxf(bf2f((ushort)(U)[3]) + va.w, 0.f); \
        s[4] += fmaxf(bf2f((ushort)(U)[4]) + vb.x, 0.f); \
        s[5] += fmaxf(bf2f((ushort)(U)[5]) + vb.y, 0.f); \
        s[6] += fmaxf(bf2f((ushort)(U)[6]) + vb.z, 0.f); \
        s[7] += fmaxf(bf2f((ushort)(U)[7]) + vb.w, 0.f); } while (0)

        int i = el;
        for (; i + 6 < deg; i += 8) {    // 4 rows in flight per half
            int r0 = srow[beg + i],     r1 = srow[beg + i + 2];
            int r2 = srow[beg + i + 4], r3 = srow[beg + i + 6];
            bf16x8 u0 = *reinterpret_cast<const bf16x8*>(&Ub[(size_t)r0 * 256 + c0]);
            bf16x8 u1 = *reinterpret_cast<const bf16x8*>(&Ub[(size_t)r1 * 256 + c0]);
            bf16x8 u2 = *reinterpret_cast<const bf16x8*>(&Ub[(size_t)r2 * 256 + c0]);
            bf16x8 u3 = *reinterpret_cast<const bf16x8*>(&Ub[(size_t)r3 * 256 + c0]);
            ACC8(u0); ACC8(u1); ACC8(u2); ACC8(u3);
        }
        for (; i < deg; i += 2) {
            int r = srow[beg + i];
            bf16x8 u = *reinterpret_cast<const bf16x8*>(&Ub[(size_t)r * 256 + c0]);
            ACC8(u);
        }
#undef ACC8
#pragma unroll
        for (int j = 0; j < 8; ++j) s[j] += __shfl_xor(s[j], 32);
        if (el == 0) {
            union { bf16x8 v; ushort h[8]; } o;
#pragma unroll
            for (int j = 0; j < 8; ++j) o.h[j] = f2bf(s[j]);
            *reinterpret_cast<bf16x8*>(&aggb[(size_t)d * 256 + c0]) = o.v;
        }
    }
}

// ---- K4: node update GEMM + bias + relu + LayerNorm (64-node tiles) ----
// 157 blocks x 512 thr (8 waves = 2 wr x 4 wc): wave = 32 nodes x 64 cols.
// A: k<256 from xb, k>=256 from aggb (both direct bf16x8). K = 512.
__global__ __launch_bounds__(512)
void node_ln(const ushort* __restrict__ xb, const ushort* __restrict__ aggb,
             const ushort* __restrict__ Wua, const float* __restrict__ bupd,
             const float* __restrict__ gamma, const float* __restrict__ beta,
             float* __restrict__ out) {
    __shared__ float pS[64][4][2];      // [node_local][wc][sum,ssq]

    const int wave = threadIdx.x >> 6;
    const int lane = threadIdx.x & 63;
    const int ml = lane & 15, kg = lane >> 4;
    const int wr = wave >> 2, wc = wave & 3;
    const int nb = blockIdx.x * 64;

    uint arow[2];
#pragma unroll
    for (int t = 0; t < 2; ++t) {
        int n = nb + wr * 32 + t * 16 + ml;
        arow[t] = (uint)(n < NNODES ? n : NNODES - 1) * DIM;
    }

    f32x4 acc[2][4];
#pragma unroll
    for (int t = 0; t < 2; ++t)
#pragma unroll
        for (int nt = 0; nt < 4; ++nt) acc[t][nt] = (f32x4){0.f, 0.f, 0.f, 0.f};

#pragma unroll
    for (int kk = 0; kk < 8; ++kk) {                  // k in [0,256): A = xb
        bf16x8 a0 = *reinterpret_cast<const bf16x8*>(xb + arow[0] + kk * 32 + kg * 8);
        bf16x8 a1 = *reinterpret_cast<const bf16x8*>(xb + arow[1] + kk * 32 + kg * 8);
#pragma unroll
        for (int nt = 0; nt < 4; ++nt) {
            bf16x8 b = *reinterpret_cast<const bf16x8*>(Wua + kk * 8192 + (wc * 4 + nt) * 512 + lane * 8);
            acc[0][nt] = __builtin_amdgcn_mfma_f32_16x16x32_bf16(a0, b, acc[0][nt], 0, 0, 0);
            acc[1][nt] = __builtin_amdgcn_mfma_f32_16x16x32_bf16(a1, b, acc[1][nt], 0, 0, 0);
        }
    }
#pragma unroll
    for (int kk = 0; kk < 8; ++kk) {                  // k in [256,512): A = aggb
        bf16x8 a0 = *reinterpret_cast<const bf16x8*>(aggb + arow[0] + kk * 32 + kg * 8);
        bf16x8 a1 = *reinterpret_cast<const bf16x8*>(aggb + arow[1] + kk * 32 + kg * 8);
#pragma unroll
        for (int nt = 0; nt < 4; ++nt) {
            bf16x8 b = *reinterpret_cast<const bf16x8*>(Wua + 65536 + kk * 8192 + (wc * 4 + nt) * 512 + lane * 8);
            acc[0][nt] = __builtin_amdgcn_mfma_f32_16x16x32_bf16(a0, b, acc[0][nt], 0, 0, 0);
            acc[1][nt] = __builtin_amdgcn_mfma_f32_16x16x32_bf16(a1, b, acc[1][nt], 0, 0, 0);
        }
    }

    // bias + relu + per-wave LN partials (64 cols per wave)
    float sum[2][4], ssq[2][4];
#pragma unroll
    for (int t = 0; t < 2; ++t)
#pragma unroll
        for (int i = 0; i < 4; ++i) { sum[t][i] = 0.f; ssq[t][i] = 0.f; }
#pragma unroll
    for (int t = 0; t < 2; ++t)
#pragma unroll
        for (int nt = 0; nt < 4; ++nt) {
            const float bb = bupd[wc * 64 + nt * 16 + ml];
#pragma unroll
            for (int i = 0; i < 4; ++i) {
                float v = acc[t][nt][i] + bb;
                v = v > 0.f ? v : 0.f;
                acc[t][nt][i] = v;
                sum[t][i] += v;
                ssq[t][i] += v * v;
            }
        }
#pragma unroll
    for (int m = 1; m < 16; m <<= 1) {
#pragma unroll
        for (int t = 0; t < 2; ++t)
#pragma unroll
            for (int i = 0; i < 4; ++i) {
                sum[t][i] += __shfl_xor(sum[t][i], m);
                ssq[t][i] += __shfl_xor(ssq[t][i], m);
            }
    }
    if (ml == 0) {
#pragma unroll
        for (int t = 0; t < 2; ++t)
#pragma unroll
            for (int i = 0; i < 4; ++i) {
                int nl = wr * 32 + t * 16 + kg * 4 + i;
                pS[nl][wc][0] = sum[t][i];
                pS[nl][wc][1] = ssq[t][i];
            }
    }
    __syncthreads();

    float mu[2][4], rs[2][4];
#pragma unroll
    for (int t = 0; t < 2; ++t)
#pragma unroll
        for (int i = 0; i < 4; ++i) {
            int nl = wr * 32 + t * 16 + kg * 4 + i;
            float S = pS[nl][0][0] + pS[nl][1][0] + pS[nl][2][0] + pS[nl][3][0];
            float Q = pS[nl][0][1] + pS[nl][1][1] + pS[nl][2][1] + pS[nl][3][1];
            float m = S * (1.f / 256.f);
            float var = Q * (1.f / 256.f) - m * m;
            mu[t][i] = m;
            rs[t][i] = rsqrtf(var + LN_EPS);
        }
#pragma unroll
    for (int t = 0; t < 2; ++t)
#pragma unroll
        for (int nt = 0; nt < 4; ++nt) {
            const int cc = wc * 64 + nt * 16 + ml;
            const float g = gamma[cc], be = beta[cc];
#pragma unroll
            for (int i = 0; i < 4; ++i) {
                const int node = nb + wr * 32 + t * 16 + kg * 4 + i;
                if (node < NNODES)
                    out[(size_t)node * DIM + cc] = (acc[t][nt][i] - mu[t][i]) * rs[t][i] * g + be;
            }
        }
}

extern "C" void kernel_launch(void* const* d_in, const int* in_sizes, int n_in,
                              void* d_out, int out_size, void* d_ws, size_t ws_size,
                              hipStream_t stream) {
    const float* x    = (const float*)d_in[0];
    const int*   eidx = (const int*)  d_in[1];
    const float* Wm   = (const float*)d_in[2];
    const float* bm   = (const float*)d_in[3];
    const float* Wu   = (const float*)d_in[4];
    const float* bu   = (const float*)d_in[5];
    const float* gam  = (const float*)d_in[6];
    const float* bet  = (const float*)d_in[7];
    float* out = (float*)d_out;

    char* ws = (char*)d_ws;
    ushort* xb     = (ushort*)(ws);                    //  5,120,000 B
    ushort* Ub     = (ushort*)(ws +  5120000);         //  5,120,000 B
    float*  Vf     = (float*) (ws + 10240000);         // 10,240,000 B
    ushort* aggb   = (ushort*)(ws + 20480000);         //  5,120,000 B
    ushort* Wcat   = (ushort*)(ws + 25600000);         //    262,144 B
    ushort* Wua    = (ushort*)(ws + 25862144);         //    262,144 B
    int*    cnt    = (int*)   (ws + 26124288);         //     40,960 B
    int*    srow   = (int*)   (ws + 26165248);         //  3,840,000 B (end ~30 MB)

    prep_all<<<3524, 256, 0, stream>>>(x, Wm, Wu, xb, Wcat, Wua, (int4*)cnt);
    scatter_uv<<<1407, 512, 0, stream>>>(eidx, cnt, srow, xb, Wcat, bm, Ub, Vf);
    edge_combine<<<1250, 256, 0, stream>>>(Ub, Vf, srow, cnt, aggb);
    node_ln<<<157, 512, 0, stream>>>(xb, aggb, Wua, bu, gam, bet, out);
}

// Round 16
// 80.694 us; speedup vs baseline: 1.0933x; 1.0832x over previous
//
#include <hip/hip_runtime.h>
#include <hip/hip_bf16.h>
#include <stdint.h>

#define NNODES 10000
#define NEDGES 320000
#define DIM    256
#define KTOT   512
#define LN_EPS 1e-5f
#define BCAP   96     // per-node bucket capacity (max degree; P(exceed) ~ 1e-20)

typedef __attribute__((ext_vector_type(4))) float f32x4;
typedef __attribute__((ext_vector_type(8))) short bf16x8;

__device__ __forceinline__ ushort f2bf(float f) {
    union { float f; uint32_t u; } v; v.f = f;
    uint32_t r = v.u + 0x7fffu + ((v.u >> 16) & 1u);   // RNE
    return (ushort)(r >> 16);
}
__device__ __forceinline__ float bf2f(ushort u) {
    union { float f; uint32_t u; } v; v.u = ((uint32_t)u) << 16;
    return v.f;
}

// ---- K1: prep — cast x->bf16, zero cnt, fragment-arrange both W matrices ----
__global__ __launch_bounds__(256)
void prep_all(const float* __restrict__ x, const float* __restrict__ Wm,
              const float* __restrict__ Wu, ushort* __restrict__ xb,
              ushort* __restrict__ Wcat, ushort* __restrict__ Wua,
              int4* __restrict__ cntz) {
    int tid = blockIdx.x * 256 + threadIdx.x;          // 3524*256 = 902144
    if (tid < 2560) cntz[tid] = (int4){0, 0, 0, 0};    // 10240 ints >= NNODES
    if (tid < 640000) {                                // x cast, one float4 each
        float4 v = reinterpret_cast<const float4*>(x)[tid];
        ushort4 o;
        o.x = f2bf(v.x); o.y = f2bf(v.y); o.z = f2bf(v.z); o.w = f2bf(v.w);
        reinterpret_cast<ushort4*>(xb)[tid] = o;
    } else {
        int t = tid - 640000;                          // < 262144
        if (t < 131072) {
            int kk  = t >> 14;
            int rem = t & 16383;
            int g   = rem >> 9;
            int kg  = (rem >> 7) & 3;
            int ml  = (rem >> 3) & 15;
            int j   = rem & 7;
            int k = kk * 32 + kg * 8 + j;
            int n = g * 16 + ml;
            float v = (n < 256) ? Wm[k * DIM + n] : Wm[(k + 256) * DIM + (n - 256)];
            Wcat[t] = f2bf(v);
        } else {
            int rem = t - 131072;
            int kk  = rem >> 13;
            int nt  = (rem >> 9) & 15;
            int kg  = (rem >> 7) & 3;
            int ml  = (rem >> 3) & 15;
            int j   = rem & 7;
            int k = kk * 32 + kg * 8 + j;
            int n = nt * 16 + ml;
            Wua[rem] = f2bf(Wu[k * DIM + n]);
        }
    }
}

// ---- K2: ILP bucket scatter (blocks [0,320)) ∥ U|V GEMM (blocks [320,945)) ----
// Scatter: 4 grid-strided edges per thread -> 4 independent atomic round-trips
// in flight. srow is ushort (node id < 2^16): half the write traffic.
__global__ __launch_bounds__(256)
void scatter_uv(const int* __restrict__ eidx, int* __restrict__ cnt,
                ushort* __restrict__ srow, const ushort* __restrict__ xb,
                const ushort* __restrict__ Wcat, const float* __restrict__ bmsg,
                ushort* __restrict__ Ub, float* __restrict__ Vf) {
    if (blockIdx.x < 320) {
        const int t = blockIdx.x * 256 + threadIdx.x;  // 0..81919
        int d[4], r[4];
#pragma unroll
        for (int j = 0; j < 3; ++j) {                  // e < 245760 always valid
            int e = t + j * 81920;
            d[j] = eidx[NEDGES + e];
            r[j] = eidx[e];
        }
        const bool ok3 = t < (NEDGES - 3 * 81920);     // 74240
        if (ok3) { d[3] = eidx[NEDGES + t + 245760]; r[3] = eidx[t + 245760]; }
        int p[4];
#pragma unroll
        for (int j = 0; j < 3; ++j) p[j] = atomicAdd(&cnt[d[j]], 1);
        if (ok3) p[3] = atomicAdd(&cnt[d[3]], 1);
#pragma unroll
        for (int j = 0; j < 3; ++j)
            if (p[j] < BCAP) srow[d[j] * BCAP + p[j]] = (ushort)r[j];
        if (ok3 && p[3] < BCAP) srow[d[3] * BCAP + p[3]] = (ushort)r[3];
        return;
    }
    // U = x @ W_msg[:256] (bf16), V = x @ W_msg[256:] + b (fp32).
    // 625 blocks x 256 thr; block = 16 nodes x 512 cols; wave wq owns 128 cols.
    const int wq   = threadIdx.x >> 6;
    const int lane = threadIdx.x & 63;
    const int ml = lane & 15, kg = lane >> 4;
    const int nb = (blockIdx.x - 320) * 16;
    const uint arow = (uint)(nb + ml) * DIM;

    f32x4 acc[8];
#pragma unroll
    for (int nt = 0; nt < 8; ++nt) acc[nt] = (f32x4){0.f, 0.f, 0.f, 0.f};

#pragma unroll
    for (int kk = 0; kk < 8; ++kk) {
        bf16x8 a = *reinterpret_cast<const bf16x8*>(xb + arow + kk * 32 + kg * 8);
#pragma unroll
        for (int nt = 0; nt < 8; ++nt) {
            bf16x8 b = *reinterpret_cast<const bf16x8*>(Wcat + kk * 16384 + (wq * 8 + nt) * 512 + lane * 8);
            acc[nt] = __builtin_amdgcn_mfma_f32_16x16x32_bf16(a, b, acc[nt], 0, 0, 0);
        }
    }

    if (wq < 2) {                                   // U half: bf16
#pragma unroll
        for (int nt = 0; nt < 8; ++nt) {
            const int col = wq * 128 + nt * 16 + ml;
#pragma unroll
            for (int i = 0; i < 4; ++i)
                Ub[(size_t)(nb + kg * 4 + i) * 256 + col] = f2bf(acc[nt][i]);
        }
    } else {                                        // V half: fp32, bias folded
#pragma unroll
        for (int nt = 0; nt < 8; ++nt) {
            const int col = (wq - 2) * 128 + nt * 16 + ml;
            const float bb = bmsg[col];
#pragma unroll
            for (int i = 0; i < 4; ++i)
                Vf[(size_t)(nb + kg * 4 + i) * 256 + col] = acc[nt][i] + bb;
        }
    }
}

// ---- K3: edge combine (standalone): aggb[d] = bf16( sum relu(U[src] + V[d]) )
// 1250 blocks x 256 thr (4 waves); wave reduces 2 nodes; lane owns 8 cols
// (16B loads); 32-lane halves split edges by parity, 4-deep ILP, one
// shfl_xor(32) combine, bf16x8 store.
__global__ __launch_bounds__(256)
void edge_combine(const ushort* __restrict__ Ub, const float* __restrict__ Vf,
                  const ushort* __restrict__ srow, const int* __restrict__ cnt,
                  ushort* __restrict__ aggb) {
    const int wave = threadIdx.x >> 6, lane = threadIdx.x & 63;
    const int nb = blockIdx.x * 8;
    const int el = lane >> 5;           // half id (edge-parity)
    const int cl = lane & 31;
    const int c0 = cl * 8;              // 8 cols owned

#pragma unroll
    for (int nn = 0; nn < 2; ++nn) {
        const int d = nb + wave * 2 + nn;
        int deg = cnt[d]; deg = deg < BCAP ? deg : BCAP;
        const int beg = d * BCAP;
        const float4 va = *reinterpret_cast<const float4*>(&Vf[(size_t)d * 256 + c0]);
        const float4 vb = *reinterpret_cast<const float4*>(&Vf[(size_t)d * 256 + c0 + 4]);
        float s[8];
#pragma unroll
        for (int j = 0; j < 8; ++j) s[j] = 0.f;

#define ACC8(U) do { \
        s[0] += fmaxf(bf2f((ushort)(U)[0]) + va.x, 0.f); \
        s[1] += fmaxf(bf2f((ushort)(U)[1]) + va.y, 0.f); \
        s[2] += fmaxf(bf2f((ushort)(U)[2]) + va.z, 0.f); \
        s[3] += fmaxf(bf2f((ushort)(U)[3]) + va.w, 0.f); \
        s[4] += fmaxf(bf2f((ushort)(U)[4]) + vb.x, 0.f); \
        s[5] += fmaxf(bf2f((ushort)(U)[5]) + vb.y, 0.f); \
        s[6] += fmaxf(bf2f((ushort)(U)[6]) + vb.z, 0.f); \
        s[7] += fmaxf(bf2f((ushort)(U)[7]) + vb.w, 0.f); } while (0)

        int i = el;
        for (; i + 6 < deg; i += 8) {    // 4 rows in flight per half
            int r0 = srow[beg + i],     r1 = srow[beg + i + 2];
            int r2 = srow[beg + i + 4], r3 = srow[beg + i + 6];
            bf16x8 u0 = *reinterpret_cast<const bf16x8*>(&Ub[(size_t)r0 * 256 + c0]);
            bf16x8 u1 = *reinterpret_cast<const bf16x8*>(&Ub[(size_t)r1 * 256 + c0]);
            bf16x8 u2 = *reinterpret_cast<const bf16x8*>(&Ub[(size_t)r2 * 256 + c0]);
            bf16x8 u3 = *reinterpret_cast<const bf16x8*>(&Ub[(size_t)r3 * 256 + c0]);
            ACC8(u0); ACC8(u1); ACC8(u2); ACC8(u3);
        }
        for (; i < deg; i += 2) {
            int r = srow[beg + i];
            bf16x8 u = *reinterpret_cast<const bf16x8*>(&Ub[(size_t)r * 256 + c0]);
            ACC8(u);
        }
#undef ACC8
#pragma unroll
        for (int j = 0; j < 8; ++j) s[j] += __shfl_xor(s[j], 32);
        if (el == 0) {
            union { bf16x8 v; ushort h[8]; } o;
#pragma unroll
            for (int j = 0; j < 8; ++j) o.h[j] = f2bf(s[j]);
            *reinterpret_cast<bf16x8*>(&aggb[(size_t)d * 256 + c0]) = o.v;
        }
    }
}

// ---- K4: node update GEMM + bias + relu + LayerNorm (64-node tiles) ----
// 157 blocks x 512 thr (8 waves = 2 wr x 4 wc): wave = 32 nodes x 64 cols.
__global__ __launch_bounds__(512)
void node_ln(const ushort* __restrict__ xb, const ushort* __restrict__ aggb,
             const ushort* __restrict__ Wua, const float* __restrict__ bupd,
             const float* __restrict__ gamma, const float* __restrict__ beta,
             float* __restrict__ out) {
    __shared__ float pS[64][4][2];      // [node_local][wc][sum,ssq]

    const int wave = threadIdx.x >> 6;
    const int lane = threadIdx.x & 63;
    const int ml = lane & 15, kg = lane >> 4;
    const int wr = wave >> 2, wc = wave & 3;
    const int nb = blockIdx.x * 64;

    uint arow[2];
#pragma unroll
    for (int t = 0; t < 2; ++t) {
        int n = nb + wr * 32 + t * 16 + ml;
        arow[t] = (uint)(n < NNODES ? n : NNODES - 1) * DIM;
    }

    f32x4 acc[2][4];
#pragma unroll
    for (int t = 0; t < 2; ++t)
#pragma unroll
        for (int nt = 0; nt < 4; ++nt) acc[t][nt] = (f32x4){0.f, 0.f, 0.f, 0.f};

#pragma unroll
    for (int kk = 0; kk < 8; ++kk) {                  // k in [0,256): A = xb
        bf16x8 a0 = *reinterpret_cast<const bf16x8*>(xb + arow[0] + kk * 32 + kg * 8);
        bf16x8 a1 = *reinterpret_cast<const bf16x8*>(xb + arow[1] + kk * 32 + kg * 8);
#pragma unroll
        for (int nt = 0; nt < 4; ++nt) {
            bf16x8 b = *reinterpret_cast<const bf16x8*>(Wua + kk * 8192 + (wc * 4 + nt) * 512 + lane * 8);
            acc[0][nt] = __builtin_amdgcn_mfma_f32_16x16x32_bf16(a0, b, acc[0][nt], 0, 0, 0);
            acc[1][nt] = __builtin_amdgcn_mfma_f32_16x16x32_bf16(a1, b, acc[1][nt], 0, 0, 0);
        }
    }
#pragma unroll
    for (int kk = 0; kk < 8; ++kk) {                  // k in [256,512): A = aggb
        bf16x8 a0 = *reinterpret_cast<const bf16x8*>(aggb + arow[0] + kk * 32 + kg * 8);
        bf16x8 a1 = *reinterpret_cast<const bf16x8*>(aggb + arow[1] + kk * 32 + kg * 8);
#pragma unroll
        for (int nt = 0; nt < 4; ++nt) {
            bf16x8 b = *reinterpret_cast<const bf16x8*>(Wua + 65536 + kk * 8192 + (wc * 4 + nt) * 512 + lane * 8);
            acc[0][nt] = __builtin_amdgcn_mfma_f32_16x16x32_bf16(a0, b, acc[0][nt], 0, 0, 0);
            acc[1][nt] = __builtin_amdgcn_mfma_f32_16x16x32_bf16(a1, b, acc[1][nt], 0, 0, 0);
        }
    }

    float sum[2][4], ssq[2][4];
#pragma unroll
    for (int t = 0; t < 2; ++t)
#pragma unroll
        for (int i = 0; i < 4; ++i) { sum[t][i] = 0.f; ssq[t][i] = 0.f; }
#pragma unroll
    for (int t = 0; t < 2; ++t)
#pragma unroll
        for (int nt = 0; nt < 4; ++nt) {
            const float bb = bupd[wc * 64 + nt * 16 + ml];
#pragma unroll
            for (int i = 0; i < 4; ++i) {
                float v = acc[t][nt][i] + bb;
                v = v > 0.f ? v : 0.f;
                acc[t][nt][i] = v;
                sum[t][i] += v;
                ssq[t][i] += v * v;
            }
        }
#pragma unroll
    for (int m = 1; m < 16; m <<= 1) {
#pragma unroll
        for (int t = 0; t < 2; ++t)
#pragma unroll
            for (int i = 0; i < 4; ++i) {
                sum[t][i] += __shfl_xor(sum[t][i], m);
                ssq[t][i] += __shfl_xor(ssq[t][i], m);
            }
    }
    if (ml == 0) {
#pragma unroll
        for (int t = 0; t < 2; ++t)
#pragma unroll
            for (int i = 0; i < 4; ++i) {
                int nl = wr * 32 + t * 16 + kg * 4 + i;
                pS[nl][wc][0] = sum[t][i];
                pS[nl][wc][1] = ssq[t][i];
            }
    }
    __syncthreads();

    float mu[2][4], rs[2][4];
#pragma unroll
    for (int t = 0; t < 2; ++t)
#pragma unroll
        for (int i = 0; i < 4; ++i) {
            int nl = wr * 32 + t * 16 + kg * 4 + i;
            float S = pS[nl][0][0] + pS[nl][1][0] + pS[nl][2][0] + pS[nl][3][0];
            float Q = pS[nl][0][1] + pS[nl][1][1] + pS[nl][2][1] + pS[nl][3][1];
            float m = S * (1.f / 256.f);
            float var = Q * (1.f / 256.f) - m * m;
            mu[t][i] = m;
            rs[t][i] = rsqrtf(var + LN_EPS);
        }
#pragma unroll
    for (int t = 0; t < 2; ++t)
#pragma unroll
        for (int nt = 0; nt < 4; ++nt) {
            const int cc = wc * 64 + nt * 16 + ml;
            const float g = gamma[cc], be = beta[cc];
#pragma unroll
            for (int i = 0; i < 4; ++i) {
                const int node = nb + wr * 32 + t * 16 + kg * 4 + i;
                if (node < NNODES)
                    out[(size_t)node * DIM + cc] = (acc[t][nt][i] - mu[t][i]) * rs[t][i] * g + be;
            }
        }
}

extern "C" void kernel_launch(void* const* d_in, const int* in_sizes, int n_in,
                              void* d_out, int out_size, void* d_ws, size_t ws_size,
                              hipStream_t stream) {
    const float* x    = (const float*)d_in[0];
    const int*   eidx = (const int*)  d_in[1];
    const float* Wm   = (const float*)d_in[2];
    const float* bm   = (const float*)d_in[3];
    const float* Wu   = (const float*)d_in[4];
    const float* bu   = (const float*)d_in[5];
    const float* gam  = (const float*)d_in[6];
    const float* bet  = (const float*)d_in[7];
    float* out = (float*)d_out;

    char* ws = (char*)d_ws;
    ushort* xb     = (ushort*)(ws);                    //  5,120,000 B
    ushort* Ub     = (ushort*)(ws +  5120000);         //  5,120,000 B
    float*  Vf     = (float*) (ws + 10240000);         // 10,240,000 B
    ushort* aggb   = (ushort*)(ws + 20480000);         //  5,120,000 B
    ushort* Wcat   = (ushort*)(ws + 25600000);         //    262,144 B
    ushort* Wua    = (ushort*)(ws + 25862144);         //    262,144 B
    int*    cnt    = (int*)   (ws + 26124288);         //     40,960 B
    ushort* srow   = (ushort*)(ws + 26165248);         //  1,920,000 B (end ~28.1 MB)

    prep_all<<<3524, 256, 0, stream>>>(x, Wm, Wu, xb, Wcat, Wua, (int4*)cnt);
    scatter_uv<<<945, 256, 0, stream>>>(eidx, cnt, srow, xb, Wcat, bm, Ub, Vf);
    edge_combine<<<1250, 256, 0, stream>>>(Ub, Vf, srow, cnt, aggb);
    node_ln<<<157, 512, 0, stream>>>(xb, aggb, Wua, bu, gam, bet, out);
}